// Round 1
// baseline (689.696 us; speedup 1.0000x reference)
//
#include <hip/hip_runtime.h>
#include <cmath>

// Problem constants
#define HH    128
#define WW    128
#define CCH   256
#define BATCH 8
#define NPLANE (BATCH*CCH)          // 2048 planes
#define PLANE_ELEMS (HH*WW)         // 16384 floats per plane

// Padded LDS plane: 3-row top/bottom border, 4-col left border (alignment), zeros
#define TB   3
#define STR  136                    // padded row stride in floats (16B-aligned)
#define S4   34                     // stride in float4
#define HPAD 134                    // 3 + 128 + 3
#define PLANE_LDS (HPAD*STR)        // 18224 floats = 72,896 B per buffer

// ---------------------------------------------------------------------------
// Fused conv pass over one plane held in LDS.
// Thread (tx,ty) owns an 8x8 output tile at (y0=8*ty, x0=8*tx).
// Register window: 7 rows x 16 floats covering plane cols x0-4 .. x0+11
// (window starts at padded col 8*tx, 16B aligned -> ds_read_b128).
// Tap (ky,kx) for output ox reads window[(o+ky)%7][ox+kx+1].
// SAVE_BX=1: init acc=0, save result to bx[] (this is the Bx pass).
// SAVE_BX=0: init acc=bx[] (A-recurrence step).
// ---------------------------------------------------------------------------
template<int SAVE_BX>
__device__ __forceinline__ void conv_pass(const float* src, float* dst,
                                          const float* cf, float* bx,
                                          int tx, int ty)
{
    const int x4 = tx * 2;          // float4 col of window start (8*tx / 4)
    const int y0 = ty * 8;
    __align__(16) float wd[7][16];
    const float4* s4 = (const float4*)src;
    float4* d4 = (float4*)dst;

#pragma unroll
    for (int r = 0; r < 7; r++) {
        const float4* row = s4 + (y0 + r) * S4 + x4;
        float4 a = row[0], b = row[1], c = row[2], d = row[3];
        *(float4*)&wd[r][0]  = a;  *(float4*)&wd[r][4]  = b;
        *(float4*)&wd[r][8]  = c;  *(float4*)&wd[r][12] = d;
    }

#pragma unroll
    for (int o = 0; o < 8; o++) {
        if (o > 0) {
            const int slot = (o + 6) % 7;
            const float4* row = s4 + (y0 + o + 6) * S4 + x4;
            float4 a = row[0], b = row[1], c = row[2], d = row[3];
            *(float4*)&wd[slot][0]  = a;  *(float4*)&wd[slot][4]  = b;
            *(float4*)&wd[slot][8]  = c;  *(float4*)&wd[slot][12] = d;
        }
        float acc[8];
#pragma unroll
        for (int i = 0; i < 8; i++) acc[i] = SAVE_BX ? 0.0f : bx[o * 8 + i];
#pragma unroll
        for (int ky = 0; ky < 7; ky++) {
            const int s = (o + ky) % 7;
#pragma unroll
            for (int kx = 0; kx < 7; kx++) {
                const float k = cf[ky * 7 + kx];
#pragma unroll
                for (int i = 0; i < 8; i++)
                    acc[i] = fmaf(wd[s][i + kx + 1], k, acc[i]);
            }
        }
        if (SAVE_BX) {
#pragma unroll
            for (int i = 0; i < 8; i++) bx[o * 8 + i] = acc[i];
        }
        float4 lo = make_float4(acc[0], acc[1], acc[2], acc[3]);
        float4 hi = make_float4(acc[4], acc[5], acc[6], acc[7]);
        float4* drow = d4 + (y0 + o + TB) * S4 + (tx * 2 + 1);
        drow[0] = lo;
        drow[1] = hi;
    }
}

// ---------------------------------------------------------------------------
// Main fused SSM kernel: one block per (b,c) plane. Reads plane-major input
// from `planes`, runs Bx pass + 7 A-steps entirely in LDS, writes h8 back
// in-place (same plane location) for the output transpose kernel.
// ---------------------------------------------------------------------------
__global__ __launch_bounds__(256, 1) void ssm_kernel(float* planes,
                                                     const float* __restrict__ Ak,
                                                     const float* __restrict__ Bk)
{
    __shared__ float buf[2 * PLANE_LDS];   // 145,792 B (gfx950: 160 KiB/CU)
    const int p  = blockIdx.x;
    const int c  = p & (CCH - 1);
    const int t  = threadIdx.x;
    const int tx = t & 15, ty = t >> 4;

    // zero both LDS buffers (borders must be 0; interior overwritten below)
    float4* z = (float4*)buf;
    const int n4 = 2 * PLANE_LDS / 4;      // 9112
    for (int i = t; i < n4; i += 256) z[i] = make_float4(0.f, 0.f, 0.f, 0.f);

    // B-kernel taps: block-uniform -> scalar loads
    float bco[49];
#pragma unroll
    for (int i = 0; i < 49; i++) bco[i] = Bk[i * CCH + c];

    __syncthreads();

    // load x plane into buf0 interior (coalesced 16B/lane)
    const float4* gx = (const float4*)planes + (size_t)p * (PLANE_ELEMS / 4);
#pragma unroll
    for (int i = 0; i < 16; i++) {
        int idx = i * 256 + t, y = idx >> 5, xc = idx & 31;
        ((float4*)buf)[(y + TB) * S4 + xc + 1] = gx[idx];
    }
    __syncthreads();

    // Pass 1: h1 = Bx = conv(x, B); also keep Bx in registers
    float bx[64];
    conv_pass<1>(buf, buf + PLANE_LDS, bco, bx, tx, ty);

    // A_stable taps: 0.9*tanh(A), forced to SGPR via readfirstlane
    float aco[49];
#pragma unroll
    for (int i = 0; i < 49; i++) {
        float v = 0.9f * tanhf(Ak[i * CCH + c]);
        aco[i] = __uint_as_float(__builtin_amdgcn_readfirstlane(__float_as_uint(v)));
    }
    __syncthreads();

    // 7 recurrence steps: h_{t+1} = conv(h_t, A_stable) + Bx
    for (int s = 0; s < 7; s++) {
        const float* src = buf + (1 - (s & 1)) * PLANE_LDS;
        float* dst       = buf + (s & 1) * PLANE_LDS;
        conv_pass<0>(src, dst, aco, bx, tx, ty);
        __syncthreads();
    }

    // h8 is in buf[0 .. PLANE_LDS); write back in-place (plane-major)
    float4* gout = (float4*)planes + (size_t)p * (PLANE_ELEMS / 4);
#pragma unroll
    for (int i = 0; i < 16; i++) {
        int idx = i * 256 + t, y = idx >> 5, xc = idx & 31;
        gout[idx] = ((float4*)buf)[(y + TB) * S4 + xc + 1];
    }
}

// ---------------------------------------------------------------------------
// NHWC -> plane-major transpose. Per batch b: M[hw=16384][c=256] -> T[c][hw].
// 64x64 tiles, float4 global access both sides, scalar LDS (pad 65 -> ~2-way).
// ---------------------------------------------------------------------------
__global__ __launch_bounds__(256) void transpose_in(const float* __restrict__ x,
                                                    float* __restrict__ xt)
{
    __shared__ float tile[64][65];
    const int p = blockIdx.x;                 // 8 * 256 * 4 = 8192 blocks
    const int b = p >> 10, rem = p & 1023, thw = rem >> 2, tc = rem & 3;
    const int t = threadIdx.x;
    const int m = t & 15, g = t >> 4;

    const size_t inbase = ((size_t)(b * 16384 + thw * 64)) * 256 + tc * 64;
#pragma unroll
    for (int i = 0; i < 4; i++) {
        int r = i * 16 + g;
        float4 v = *(const float4*)(x + inbase + (size_t)r * 256 + m * 4);
        tile[r][m * 4 + 0] = v.x; tile[r][m * 4 + 1] = v.y;
        tile[r][m * 4 + 2] = v.z; tile[r][m * 4 + 3] = v.w;
    }
    __syncthreads();
    const size_t outbase = ((size_t)(b * 256 + tc * 64)) * 16384 + thw * 64;
#pragma unroll
    for (int i = 0; i < 4; i++) {
        int cr = i * 16 + g;
        float4 v = make_float4(tile[m * 4 + 0][cr], tile[m * 4 + 1][cr],
                               tile[m * 4 + 2][cr], tile[m * 4 + 3][cr]);
        *(float4*)(xt + outbase + (size_t)cr * 16384 + m * 4) = v;
    }
}

// plane-major -> NHWC (inverse of the above)
__global__ __launch_bounds__(256) void transpose_out(const float* __restrict__ ht,
                                                     float* __restrict__ out)
{
    __shared__ float tile[64][65];
    const int p = blockIdx.x;
    const int b = p >> 10, rem = p & 1023, thw = rem >> 2, tc = rem & 3;
    const int t = threadIdx.x;
    const int m = t & 15, g = t >> 4;

    const size_t inbase = ((size_t)(b * 256 + tc * 64)) * 16384 + thw * 64;
#pragma unroll
    for (int i = 0; i < 4; i++) {
        int cr = i * 16 + g;
        float4 v = *(const float4*)(ht + inbase + (size_t)cr * 16384 + m * 4);
        tile[cr][m * 4 + 0] = v.x; tile[cr][m * 4 + 1] = v.y;
        tile[cr][m * 4 + 2] = v.z; tile[cr][m * 4 + 3] = v.w;
    }
    __syncthreads();
    const size_t outbase = ((size_t)(b * 16384 + thw * 64)) * 256 + tc * 64;
#pragma unroll
    for (int i = 0; i < 4; i++) {
        int r = i * 16 + g;
        float4 v = make_float4(tile[m * 4 + 0][r], tile[m * 4 + 1][r],
                               tile[m * 4 + 2][r], tile[m * 4 + 3][r]);
        *(float4*)(out + outbase + (size_t)r * 256 + m * 4) = v;
    }
}

extern "C" void kernel_launch(void* const* d_in, const int* in_sizes, int n_in,
                              void* d_out, int out_size, void* d_ws, size_t ws_size,
                              hipStream_t stream)
{
    (void)in_sizes; (void)n_in; (void)out_size; (void)ws_size;
    const float* x  = (const float*)d_in[0];
    const float* Ak = (const float*)d_in[1];
    const float* Bk = (const float*)d_in[2];
    float* out    = (float*)d_out;
    float* planes = (float*)d_ws;     // needs 128 MiB scratch

    transpose_in <<<8192, 256, 0, stream>>>(x, planes);
    ssm_kernel   <<<NPLANE, 256, 0, stream>>>(planes, Ak, Bk);
    transpose_out<<<8192, 256, 0, stream>>>(planes, out);
}